// Round 2
// baseline (333.634 us; speedup 1.0000x reference)
//
#include <hip/hip_runtime.h>
#include <stdint.h>

#define T_ 128

typedef int v4i __attribute__((ext_vector_type(4)));

// ---------------------------------------------------------------------------
// prep 1: static B-fragments for mfma_i32_16x16x64_i8, biased i8 (byte-128).
// Fragment mf = (tau*5 + kappa)*2 + h. Lane l holds n = l&15,
// k-slots kin = (l>>4)*16 + 4r + b — identical slot->k map as scan's A, so
// any HW k-permutation cancels in the dot.
__global__ void prep_bfrag(const int* __restrict__ sc, uint4* __restrict__ bf) {
  int gid = blockIdx.x * 256 + threadIdx.x;
  if (gid >= 160 * 64) return;
  int mf = gid >> 6, l = gid & 63;
  int tau = mf / 10, rem = mf % 10;
  int kap = rem >> 1, h = rem & 1;
  int j = 16 * tau + (l & 15);
  int kinb = (l >> 4) * 16;
  unsigned wout[4];
#pragma unroll
  for (int r = 0; r < 4; ++r) {
    unsigned wrd = 0;
#pragma unroll
    for (int be = 0; be < 4; ++be) {
      int kin = kinb + 4 * r + be;
      int col = (kap == 0) ? kin : 64 + ((kap - 1) << 6) + kin;
      unsigned c = (unsigned)sc[j * 320 + col];
      unsigned byte = (h ? (c >> 8) : c) & 0xFFu;
      byte = (byte - 128u) & 0xFFu;
      wrd |= byte << (8 * be);
    }
    wout[r] = wrd;
  }
  bf[gid] = make_uint4(wout[0], wout[1], wout[2], wout[3]);
}

// prep 2: window bits packed to u64 per (b,t)
__global__ void prep_wbits(const int* __restrict__ bits,
                           unsigned long long* __restrict__ wb) {
  int gid = blockIdx.x * 256 + threadIdx.x;
  int wv = gid >> 6, lane = gid & 63;
  unsigned long long m = __ballot(bits[gid] != 0);
  if (lane == 0) wb[wv] = m;
}

// prep 3: bitpack (state_mem >= 0.5) -> 2 MiB table (L2-resident for scan)
__global__ void prep_bitpack(const float* __restrict__ sm,
                             unsigned long long* __restrict__ packed) {
  int base = blockIdx.x * (256 * 32) + threadIdx.x;
  int lane = threadIdx.x & 63;
#pragma unroll 1
  for (int it = 0; it < 32; ++it) {
    int idx = base + it * 256;
    float v = sm[idx];
    unsigned long long m = __ballot(v >= 0.5f);
    if (lane == 0) packed[idx >> 6] = m;
  }
}

// ---------------------------------------------------------------------------
// per-lane expand of a 16-bit slice into an i8 {0,1} A-fragment
static __device__ __forceinline__ v4i expand16(unsigned b16) {
  v4i a;
#pragma unroll
  for (int r = 0; r < 4; ++r) {
    unsigned nib = (b16 >> (4 * r)) & 0xFu;
    a[r] = (int)((nib * 0x00204081u) & 0x01010101u);
  }
  return a;
}

// ---------------------------------------------------------------------------
// prep 4: hoist the window contribution out of the scan. For every (b,t)
// row m and every state j: win[m][j] = (sum_k w_k * c_jk) mod 2^16, computed
// with the EXACT same broadcast-A + bfrag-chunk-0 MFMA path the scan loop
// used (verified math; no A-row-layout assumption). One wave per 4 rows.
__global__ void prep_wgemm(const uint4* __restrict__ bfrag,
                           const unsigned long long* __restrict__ wb,
                           unsigned short* __restrict__ win) {
  int wave = blockIdx.x * 4 + (threadIdx.x >> 6);
  int l = threadIdx.x & 63;
  int qq = l >> 4;
  v4i z = (v4i){0, 0, 0, 0};
#pragma unroll 1
  for (int mi = 0; mi < 4; ++mi) {
    int m = wave * 4 + mi;
    unsigned long long wrow = wb[m];
    v4i aw = expand16((unsigned)((wrow >> (16 * qq)) & 0xFFFFu));
    unsigned corr = (unsigned)__popcll(wrow) * 32896u;
#pragma unroll 1
    for (int tau = 0; tau < 16; ++tau) {
      v4i blo = __builtin_bit_cast(v4i, bfrag[(tau * 10 + 0) * 64 + l]);
      v4i bhi = __builtin_bit_cast(v4i, bfrag[(tau * 10 + 1) * 64 + l]);
      v4i alo = __builtin_amdgcn_mfma_i32_16x16x64_i8(aw, blo, z, 0, 0, 0);
      v4i ahi = __builtin_amdgcn_mfma_i32_16x16x64_i8(aw, bhi, z, 0, 0, 0);
      if (l < 16) {
        unsigned ad = ((unsigned)alo[0] + ((unsigned)ahi[0] << 8) + corr) & 0xFFFFu;
        win[(size_t)m * 256 + tau * 16 + l] = (unsigned short)ad;
      }
    }
  }
}

// ---------------------------------------------------------------------------
// scan + heads: 1 block per batch row, 4 waves of 64. Wave w owns states
// j in [64w, 64w+64). Per step: ds_read A-frags from byte table, 32 state
// MFMAs in TWO 2-deep chains (accA: chunks 0,1; accB: chunks 2,3), epilogue
// adds prefetched window term + popcount fixup, self-gather one bit/lane,
// raw s_barrier with lgkmcnt-only drain (global prefetches stay in flight).
__global__ __launch_bounds__(256, 1) void scan_heads(
    const uint4* __restrict__ bfrag,
    const unsigned short* __restrict__ win,
    const unsigned* __restrict__ packed32,
    const unsigned long long* __restrict__ wbits,
    const int* __restrict__ head_conn,
    const int* __restrict__ head_coeffs,
    const float* __restrict__ head_mem,
    float* __restrict__ out) {
  __shared__ __align__(16) unsigned char ab[2][256];   // state bits as i8 bytes
  __shared__ __align__(16) unsigned mcnt[2][4];        // per-chunk popcnt*32896
  const int tid = threadIdx.x;
  const int b = blockIdx.x;
  const int w = tid >> 6, l = tid & 63;
  const int qq = l >> 4;
  const int j = 64 * w + l;

  // one-time: 32 static state-chunk B-fragments (kappa 1..4) into registers
  v4i bf[4][4][2];
#pragma unroll
  for (int i = 0; i < 4; ++i)
#pragma unroll
    for (int c = 0; c < 4; ++c)
#pragma unroll
      for (int h = 0; h < 2; ++h) {
        int mf = ((4 * w + i) * 5 + (c + 1)) * 2 + h;
        bf[i][c][h] = __builtin_bit_cast(v4i, bfrag[mf * 64 + l]);
      }

  ab[0][tid] = (unsigned char)0;            // state0 = 0
  if (tid < 4) mcnt[0][tid] = 0u;

  const unsigned* pkrow = packed32 + ((size_t)j << 11);
  unsigned vw = (unsigned)win[(size_t)(b * 128) * 256 + j];  // t=0 window term
  __syncthreads();

#pragma unroll 2
  for (int t = 0; t < T_; ++t) {
    const int cur = t & 1, nxt = cur ^ 1;

    // LDS reads first: 4 broadcast A-frags + popcount fixups
    const unsigned char* abase = &ab[cur][16 * qq];
    v4i a0 = *(const v4i*)(abase);
    v4i a1 = *(const v4i*)(abase + 64);
    v4i a2 = *(const v4i*)(abase + 128);
    v4i a3 = *(const v4i*)(abase + 192);
    uint4 cz = *((const uint4*)&mcnt[cur][0]);

    // prefetch next step's window term (consumed next iteration)
    int tn = (t + 1 < T_) ? t + 1 : t;
    unsigned vwn = (unsigned)win[(size_t)(b * 128 + tn) * 256 + j];

    // 32 MFMAs, two independent 2-deep chains per (tile,h)
    v4i z = (v4i){0, 0, 0, 0};
    v4i accA[4][2], accB[4][2];
#pragma unroll
    for (int i = 0; i < 4; ++i) {
      accA[i][0] = __builtin_amdgcn_mfma_i32_16x16x64_i8(a0, bf[i][0][0], z, 0, 0, 0);
      accA[i][1] = __builtin_amdgcn_mfma_i32_16x16x64_i8(a0, bf[i][0][1], z, 0, 0, 0);
      accB[i][0] = __builtin_amdgcn_mfma_i32_16x16x64_i8(a2, bf[i][2][0], z, 0, 0, 0);
      accB[i][1] = __builtin_amdgcn_mfma_i32_16x16x64_i8(a2, bf[i][2][1], z, 0, 0, 0);
    }
#pragma unroll
    for (int i = 0; i < 4; ++i) {
      accA[i][0] = __builtin_amdgcn_mfma_i32_16x16x64_i8(a1, bf[i][1][0], accA[i][0], 0, 0, 0);
      accA[i][1] = __builtin_amdgcn_mfma_i32_16x16x64_i8(a1, bf[i][1][1], accA[i][1], 0, 0, 0);
      accB[i][0] = __builtin_amdgcn_mfma_i32_16x16x64_i8(a3, bf[i][3][0], accB[i][0], 0, 0, 0);
      accB[i][1] = __builtin_amdgcn_mfma_i32_16x16x64_i8(a3, bf[i][3][1], accB[i][1], 0, 0, 0);
    }

    // epilogue: lane l owns state j = 64w+l -> tile i = l>>4, col l&15, reg 0
    unsigned csum = cz.x + cz.y + cz.z + cz.w;  // 128*257 * state-popcount
    unsigned loA = (l & 16) ? (unsigned)accA[1][0][0] : (unsigned)accA[0][0][0];
    unsigned loA2 = (l & 16) ? (unsigned)accA[3][0][0] : (unsigned)accA[2][0][0];
    unsigned hiA = (l & 16) ? (unsigned)accA[1][1][0] : (unsigned)accA[0][1][0];
    unsigned hiA2 = (l & 16) ? (unsigned)accA[3][1][0] : (unsigned)accA[2][1][0];
    unsigned loB = (l & 16) ? (unsigned)accB[1][0][0] : (unsigned)accB[0][0][0];
    unsigned loB2 = (l & 16) ? (unsigned)accB[3][0][0] : (unsigned)accB[2][0][0];
    unsigned hiB = (l & 16) ? (unsigned)accB[1][1][0] : (unsigned)accB[0][1][0];
    unsigned hiB2 = (l & 16) ? (unsigned)accB[3][1][0] : (unsigned)accB[2][1][0];
    unsigned lo = ((l & 32) ? loA2 : loA) + ((l & 32) ? loB2 : loB);
    unsigned hi = ((l & 32) ? hiA2 : hiA) + ((l & 32) ? hiB2 : hiB);
    unsigned ad = (lo + (hi << 8) + csum + vw) & 0xFFFFu;

    // self-gather: one bit per lane, 256 per block
    unsigned word = pkrow[ad >> 5];
    unsigned bitv = (word >> (ad & 31)) & 1u;
    unsigned long long mq = __ballot(bitv != 0u);
    ab[nxt][j] = (unsigned char)bitv;
    if (l == 0) mcnt[nxt][w] = (unsigned)__popcll(mq) * 32896u;

    // raw barrier: drain LDS only; global prefetches stay in flight
    asm volatile("s_waitcnt lgkmcnt(0)" ::: "memory");
    __builtin_amdgcn_sched_barrier(0);
    __builtin_amdgcn_s_barrier();
    __builtin_amdgcn_sched_barrier(0);

    vw = vwn;
  }

  // ---- heads (wave 0): only the selected head per batch row
  if (w == 0) {
    unsigned long long wl = wbits[b * 128 + 127];
    int h = (int)((((wl >> 61) & 1) << 2) | (((wl >> 62) & 1) << 1) |
                  ((wl >> 63) & 1));
    int ho = h * 64 + l;
    const int4* cn4 = (const int4*)(head_conn + ho * 8);
    const int4* cf4 = (const int4*)(head_coeffs + ho * 8);
    int4 cna = cn4[0], cnb = cn4[1];
    int4 cfa = cf4[0], cfb = cf4[1];
    int cns[8] = {cna.x, cna.y, cna.z, cna.w, cnb.x, cnb.y, cnb.z, cnb.w};
    int cfs[8] = {cfa.x, cfa.y, cfa.z, cfa.w, cfb.x, cfb.y, cfb.z, cfb.w};
    unsigned addr = 0;
#pragma unroll
    for (int k = 0; k < 8; ++k) {
      addr += (unsigned)ab[T_ & 1][cns[k]] * (unsigned)cfs[k];
    }
    addr &= 0xFFFFu;
    out[b * 64 + l] = head_mem[((size_t)ho << 16) + addr];
  }
}

extern "C" void kernel_launch(void* const* d_in, const int* in_sizes, int n_in,
                              void* d_out, int out_size, void* d_ws, size_t ws_size,
                              hipStream_t stream) {
  const int*   bits         = (const int*)d_in[0];
  const int*   state_coeffs = (const int*)d_in[1];
  const float* state_mem    = (const float*)d_in[2];
  const int*   head_conn    = (const int*)d_in[3];
  const int*   head_coeffs  = (const int*)d_in[4];
  const float* head_mem     = (const float*)d_in[5];
  float* out = (float*)d_out;

  char* ws = (char*)d_ws;
  uint4*              bfrag  = (uint4*)ws;                              // 160 KiB
  unsigned long long* wbits  = (unsigned long long*)(ws + (160 << 10)); // 128 KiB
  unsigned*           packed = (unsigned*)(ws + (288 << 10));           // 2 MiB
  unsigned short*     win    = (unsigned short*)(ws + (288 << 10) + (2 << 20)); // 8 MiB

  prep_bfrag<<<40, 256, 0, stream>>>(state_coeffs, bfrag);
  prep_wbits<<<4096, 256, 0, stream>>>(bits, wbits);
  prep_bitpack<<<2048, 256, 0, stream>>>(state_mem, (unsigned long long*)packed);
  prep_wgemm<<<1024, 256, 0, stream>>>(bfrag, wbits, win);
  scan_heads<<<128, 256, 0, stream>>>(bfrag, win, packed, wbits,
                                      head_conn, head_coeffs, head_mem, out);
}

// Round 3
// 332.689 us; speedup vs baseline: 1.0028x; 1.0028x over previous
//
#include <hip/hip_runtime.h>
#include <stdint.h>

#define T_ 128

typedef int v4i __attribute__((ext_vector_type(4)));

// ---------------------------------------------------------------------------
// prep 1: static B-fragments for mfma_i32_16x16x64_i8, biased i8 (byte-128).
// Fragment mf = (tau*5 + kappa)*2 + h. Lane l holds n = l&15,
// k-slots kin = (l>>4)*16 + 4r + b — identical slot->k map as scan's A, so
// any HW k-permutation cancels in the dot.
__global__ void prep_bfrag(const int* __restrict__ sc, uint4* __restrict__ bf) {
  int gid = blockIdx.x * 256 + threadIdx.x;
  if (gid >= 160 * 64) return;
  int mf = gid >> 6, l = gid & 63;
  int tau = mf / 10, rem = mf % 10;
  int kap = rem >> 1, h = rem & 1;
  int j = 16 * tau + (l & 15);
  int kinb = (l >> 4) * 16;
  unsigned wout[4];
#pragma unroll
  for (int r = 0; r < 4; ++r) {
    unsigned wrd = 0;
#pragma unroll
    for (int be = 0; be < 4; ++be) {
      int kin = kinb + 4 * r + be;
      int col = (kap == 0) ? kin : 64 + ((kap - 1) << 6) + kin;
      unsigned c = (unsigned)sc[j * 320 + col];
      unsigned byte = (h ? (c >> 8) : c) & 0xFFu;
      byte = (byte - 128u) & 0xFFu;
      wrd |= byte << (8 * be);
    }
    wout[r] = wrd;
  }
  bf[gid] = make_uint4(wout[0], wout[1], wout[2], wout[3]);
}

// prep 2: window bits packed to u64 per (b,t)
__global__ void prep_wbits(const int* __restrict__ bits,
                           unsigned long long* __restrict__ wb) {
  int gid = blockIdx.x * 256 + threadIdx.x;
  int wv = gid >> 6, lane = gid & 63;
  unsigned long long m = __ballot(bits[gid] != 0);
  if (lane == 0) wb[wv] = m;
}

// prep 3: bitpack (state_mem >= 0.5) -> 2 MiB table (L2-resident for scan)
__global__ void prep_bitpack(const float* __restrict__ sm,
                             unsigned long long* __restrict__ packed) {
  int base = blockIdx.x * (256 * 32) + threadIdx.x;
  int lane = threadIdx.x & 63;
#pragma unroll 1
  for (int it = 0; it < 32; ++it) {
    int idx = base + it * 256;
    float v = sm[idx];
    unsigned long long m = __ballot(v >= 0.5f);
    if (lane == 0) packed[idx >> 6] = m;
  }
}

// ---------------------------------------------------------------------------
// per-lane expand of a 16-bit slice into an i8 {0,1} A-fragment
static __device__ __forceinline__ v4i expand16(unsigned b16) {
  v4i a;
#pragma unroll
  for (int r = 0; r < 4; ++r) {
    unsigned nib = (b16 >> (4 * r)) & 0xFu;
    a[r] = (int)((nib * 0x00204081u) & 0x01010101u);
  }
  return a;
}

// ---------------------------------------------------------------------------
// prep 4: hoist the window contribution out of the scan. For every (b,t)
// row m and every state j: win[m][j] = (sum_k w_k * c_jk + bias fixup) mod
// 2^16, via the same broadcast-A + bfrag-chunk-0 MFMA path as the scan.
// R3 rewrite: each wave loads its 32 B-fragments ONCE into registers
// (128 VGPRs), then streams 16 rows; all 32 MFMAs per row are independent
// (issue-bound burst instead of an L2 load chain). 1024 waves x 16 rows.
__global__ __launch_bounds__(256, 1) void prep_wgemm(
    const uint4* __restrict__ bfrag,
    const unsigned long long* __restrict__ wb,
    unsigned short* __restrict__ win) {
  int wave = blockIdx.x * 4 + (threadIdx.x >> 6);
  int l = threadIdx.x & 63;
  int qq = l >> 4;

  // one-time: 32 window B-fragments (tau 0..15, h 0..1)
  v4i bl[16], bh[16];
#pragma unroll
  for (int tau = 0; tau < 16; ++tau) {
    bl[tau] = __builtin_bit_cast(v4i, bfrag[(tau * 10 + 0) * 64 + l]);
    bh[tau] = __builtin_bit_cast(v4i, bfrag[(tau * 10 + 1) * 64 + l]);
  }

  v4i z = (v4i){0, 0, 0, 0};
#pragma unroll 1
  for (int mi = 0; mi < 16; ++mi) {
    int m = wave * 16 + mi;
    unsigned long long wrow = wb[m];
    v4i aw = expand16((unsigned)((wrow >> (16 * qq)) & 0xFFFFu));
    unsigned corr = (unsigned)__popcll(wrow) * 32896u;
    v4i alo[16], ahi[16];
#pragma unroll
    for (int tau = 0; tau < 16; ++tau) {
      alo[tau] = __builtin_amdgcn_mfma_i32_16x16x64_i8(aw, bl[tau], z, 0, 0, 0);
      ahi[tau] = __builtin_amdgcn_mfma_i32_16x16x64_i8(aw, bh[tau], z, 0, 0, 0);
    }
    if (l < 16) {
#pragma unroll
      for (int tau = 0; tau < 16; ++tau) {
        unsigned ad = ((unsigned)alo[tau][0] + ((unsigned)ahi[tau][0] << 8) + corr) & 0xFFFFu;
        win[(size_t)m * 256 + tau * 16 + l] = (unsigned short)ad;
      }
    }
  }
}

// ---------------------------------------------------------------------------
// scan + heads: 1 block per batch row, 4 waves of 64. Wave w owns states
// j in [64w, 64w+64). Per step: ds_read A-frags from byte table, 32 state
// MFMAs in TWO 2-deep chains (accA: chunks 0,1; accB: chunks 2,3), epilogue
// adds prefetched window term + popcount fixup, self-gather one bit/lane,
// raw s_barrier with lgkmcnt-only drain (global prefetches stay in flight).
__global__ __launch_bounds__(256, 1) void scan_heads(
    const uint4* __restrict__ bfrag,
    const unsigned short* __restrict__ win,
    const unsigned* __restrict__ packed32,
    const unsigned long long* __restrict__ wbits,
    const int* __restrict__ head_conn,
    const int* __restrict__ head_coeffs,
    const float* __restrict__ head_mem,
    float* __restrict__ out) {
  __shared__ __align__(16) unsigned char ab[2][256];   // state bits as i8 bytes
  __shared__ __align__(16) unsigned mcnt[2][4];        // per-chunk popcnt*32896
  const int tid = threadIdx.x;
  const int b = blockIdx.x;
  const int w = tid >> 6, l = tid & 63;
  const int qq = l >> 4;
  const int j = 64 * w + l;

  // one-time: 32 static state-chunk B-fragments (kappa 1..4) into registers
  v4i bf[4][4][2];
#pragma unroll
  for (int i = 0; i < 4; ++i)
#pragma unroll
    for (int c = 0; c < 4; ++c)
#pragma unroll
      for (int h = 0; h < 2; ++h) {
        int mf = ((4 * w + i) * 5 + (c + 1)) * 2 + h;
        bf[i][c][h] = __builtin_bit_cast(v4i, bfrag[mf * 64 + l]);
      }

  ab[0][tid] = (unsigned char)0;            // state0 = 0
  if (tid < 4) mcnt[0][tid] = 0u;

  const unsigned* pkrow = packed32 + ((size_t)j << 11);
  unsigned vw = (unsigned)win[(size_t)(b * 128) * 256 + j];  // t=0 window term
  __syncthreads();

#pragma unroll 2
  for (int t = 0; t < T_; ++t) {
    const int cur = t & 1, nxt = cur ^ 1;

    // LDS reads first: 4 broadcast A-frags + popcount fixups
    const unsigned char* abase = &ab[cur][16 * qq];
    v4i a0 = *(const v4i*)(abase);
    v4i a1 = *(const v4i*)(abase + 64);
    v4i a2 = *(const v4i*)(abase + 128);
    v4i a3 = *(const v4i*)(abase + 192);
    uint4 cz = *((const uint4*)&mcnt[cur][0]);

    // prefetch next step's window term (consumed next iteration)
    int tn = (t + 1 < T_) ? t + 1 : t;
    unsigned vwn = (unsigned)win[(size_t)(b * 128 + tn) * 256 + j];

    // 32 MFMAs, two independent 2-deep chains per (tile,h)
    v4i z = (v4i){0, 0, 0, 0};
    v4i accA[4][2], accB[4][2];
#pragma unroll
    for (int i = 0; i < 4; ++i) {
      accA[i][0] = __builtin_amdgcn_mfma_i32_16x16x64_i8(a0, bf[i][0][0], z, 0, 0, 0);
      accA[i][1] = __builtin_amdgcn_mfma_i32_16x16x64_i8(a0, bf[i][0][1], z, 0, 0, 0);
      accB[i][0] = __builtin_amdgcn_mfma_i32_16x16x64_i8(a2, bf[i][2][0], z, 0, 0, 0);
      accB[i][1] = __builtin_amdgcn_mfma_i32_16x16x64_i8(a2, bf[i][2][1], z, 0, 0, 0);
    }
#pragma unroll
    for (int i = 0; i < 4; ++i) {
      accA[i][0] = __builtin_amdgcn_mfma_i32_16x16x64_i8(a1, bf[i][1][0], accA[i][0], 0, 0, 0);
      accA[i][1] = __builtin_amdgcn_mfma_i32_16x16x64_i8(a1, bf[i][1][1], accA[i][1], 0, 0, 0);
      accB[i][0] = __builtin_amdgcn_mfma_i32_16x16x64_i8(a3, bf[i][3][0], accB[i][0], 0, 0, 0);
      accB[i][1] = __builtin_amdgcn_mfma_i32_16x16x64_i8(a3, bf[i][3][1], accB[i][1], 0, 0, 0);
    }

    // epilogue: lane l owns state j = 64w+l -> tile i = l>>4, col l&15, reg 0.
    // Combine lo+hi per tile first (sum over k-chunks is a plain add), then
    // a 2-level tile select -> shortest path from last MFMA to the gather.
    unsigned csum = cz.x + cz.y + cz.z + cz.w;  // 128*257 * state-popcount
    unsigned tv0 = ((unsigned)accA[0][0][0] + (unsigned)accB[0][0][0]) +
                   (((unsigned)accA[0][1][0] + (unsigned)accB[0][1][0]) << 8);
    unsigned tv1 = ((unsigned)accA[1][0][0] + (unsigned)accB[1][0][0]) +
                   (((unsigned)accA[1][1][0] + (unsigned)accB[1][1][0]) << 8);
    unsigned tv2 = ((unsigned)accA[2][0][0] + (unsigned)accB[2][0][0]) +
                   (((unsigned)accA[2][1][0] + (unsigned)accB[2][1][0]) << 8);
    unsigned tv3 = ((unsigned)accA[3][0][0] + (unsigned)accB[3][0][0]) +
                   (((unsigned)accA[3][1][0] + (unsigned)accB[3][1][0]) << 8);
    unsigned t01 = (l & 16) ? tv1 : tv0;
    unsigned t23 = (l & 16) ? tv3 : tv2;
    unsigned ad = (((l & 32) ? t23 : t01) + csum + vw) & 0xFFFFu;

    // self-gather: one bit per lane, 256 per block
    unsigned word = pkrow[ad >> 5];
    unsigned bitv = (word >> (ad & 31)) & 1u;
    unsigned long long mq = __ballot(bitv != 0u);
    ab[nxt][j] = (unsigned char)bitv;
    if (l == 0) mcnt[nxt][w] = (unsigned)__popcll(mq) * 32896u;

    // raw barrier: drain LDS only; global prefetches stay in flight
    asm volatile("s_waitcnt lgkmcnt(0)" ::: "memory");
    __builtin_amdgcn_sched_barrier(0);
    __builtin_amdgcn_s_barrier();
    __builtin_amdgcn_sched_barrier(0);

    vw = vwn;
  }

  // ---- heads (wave 0): only the selected head per batch row
  if (w == 0) {
    unsigned long long wl = wbits[b * 128 + 127];
    int h = (int)((((wl >> 61) & 1) << 2) | (((wl >> 62) & 1) << 1) |
                  ((wl >> 63) & 1));
    int ho = h * 64 + l;
    const int4* cn4 = (const int4*)(head_conn + ho * 8);
    const int4* cf4 = (const int4*)(head_coeffs + ho * 8);
    int4 cna = cn4[0], cnb = cn4[1];
    int4 cfa = cf4[0], cfb = cf4[1];
    int cns[8] = {cna.x, cna.y, cna.z, cna.w, cnb.x, cnb.y, cnb.z, cnb.w};
    int cfs[8] = {cfa.x, cfa.y, cfa.z, cfa.w, cfb.x, cfb.y, cfb.z, cfb.w};
    unsigned addr = 0;
#pragma unroll
    for (int k = 0; k < 8; ++k) {
      addr += (unsigned)ab[T_ & 1][cns[k]] * (unsigned)cfs[k];
    }
    addr &= 0xFFFFu;
    out[b * 64 + l] = head_mem[((size_t)ho << 16) + addr];
  }
}

extern "C" void kernel_launch(void* const* d_in, const int* in_sizes, int n_in,
                              void* d_out, int out_size, void* d_ws, size_t ws_size,
                              hipStream_t stream) {
  const int*   bits         = (const int*)d_in[0];
  const int*   state_coeffs = (const int*)d_in[1];
  const float* state_mem    = (const float*)d_in[2];
  const int*   head_conn    = (const int*)d_in[3];
  const int*   head_coeffs  = (const int*)d_in[4];
  const float* head_mem     = (const float*)d_in[5];
  float* out = (float*)d_out;

  char* ws = (char*)d_ws;
  uint4*              bfrag  = (uint4*)ws;                              // 160 KiB
  unsigned long long* wbits  = (unsigned long long*)(ws + (160 << 10)); // 128 KiB
  unsigned*           packed = (unsigned*)(ws + (288 << 10));           // 2 MiB
  unsigned short*     win    = (unsigned short*)(ws + (288 << 10) + (2 << 20)); // 8 MiB

  prep_bfrag<<<40, 256, 0, stream>>>(state_coeffs, bfrag);
  prep_wbits<<<4096, 256, 0, stream>>>(bits, wbits);
  prep_bitpack<<<2048, 256, 0, stream>>>(state_mem, (unsigned long long*)packed);
  prep_wgemm<<<256, 256, 0, stream>>>(bfrag, wbits, win);
  scan_heads<<<128, 256, 0, stream>>>(bfrag, win, packed, wbits,
                                      head_conn, head_coeffs, head_mem, out);
}

// Round 4
// 319.819 us; speedup vs baseline: 1.0432x; 1.0402x over previous
//
#include <hip/hip_runtime.h>
#include <stdint.h>

#define T_ 128

typedef int v4i __attribute__((ext_vector_type(4)));

// ---------------------------------------------------------------------------
// prep 1: static B-fragments for mfma_i32_16x16x64_i8, biased i8 (byte-128).
// Fragment mf = (tau*5 + kappa)*2 + h. Lane l holds n = l&15,
// k-slots kin = (l>>4)*16 + 4r + b — identical slot->k map as scan's A, so
// any HW k-permutation cancels in the dot.
__global__ void prep_bfrag(const int* __restrict__ sc, uint4* __restrict__ bf) {
  int gid = blockIdx.x * 256 + threadIdx.x;
  if (gid >= 160 * 64) return;
  int mf = gid >> 6, l = gid & 63;
  int tau = mf / 10, rem = mf % 10;
  int kap = rem >> 1, h = rem & 1;
  int j = 16 * tau + (l & 15);
  int kinb = (l >> 4) * 16;
  unsigned wout[4];
#pragma unroll
  for (int r = 0; r < 4; ++r) {
    unsigned wrd = 0;
#pragma unroll
    for (int be = 0; be < 4; ++be) {
      int kin = kinb + 4 * r + be;
      int col = (kap == 0) ? kin : 64 + ((kap - 1) << 6) + kin;
      unsigned c = (unsigned)sc[j * 320 + col];
      unsigned byte = (h ? (c >> 8) : c) & 0xFFu;
      byte = (byte - 128u) & 0xFFu;
      wrd |= byte << (8 * be);
    }
    wout[r] = wrd;
  }
  bf[gid] = make_uint4(wout[0], wout[1], wout[2], wout[3]);
}

// prep 2: window bits packed to u64 per (b,t)
__global__ void prep_wbits(const int* __restrict__ bits,
                           unsigned long long* __restrict__ wb) {
  int gid = blockIdx.x * 256 + threadIdx.x;
  int wv = gid >> 6, lane = gid & 63;
  unsigned long long m = __ballot(bits[gid] != 0);
  if (lane == 0) wb[wv] = m;
}

// prep 3: bitpack (state_mem >= 0.5) -> 2 MiB table (L2-resident for scan)
__global__ void prep_bitpack(const float* __restrict__ sm,
                             unsigned long long* __restrict__ packed) {
  int base = blockIdx.x * (256 * 32) + threadIdx.x;
  int lane = threadIdx.x & 63;
#pragma unroll 1
  for (int it = 0; it < 32; ++it) {
    int idx = base + it * 256;
    float v = sm[idx];
    unsigned long long m = __ballot(v >= 0.5f);
    if (lane == 0) packed[idx >> 6] = m;
  }
}

// ---------------------------------------------------------------------------
// per-lane expand of a 16-bit slice into an i8 {0,1} A-fragment (window only)
static __device__ __forceinline__ v4i expand16(unsigned b16) {
  v4i a;
#pragma unroll
  for (int r = 0; r < 4; ++r) {
    unsigned nib = (b16 >> (4 * r)) & 0xFu;
    a[r] = (int)((nib * 0x00204081u) & 0x01010101u);
  }
  return a;
}

// ---------------------------------------------------------------------------
// scan + heads: 1 block per batch row, 4 waves of 64. Wave w owns states
// j in [64w, 64w+64). Per step:
//   ds_read A-frags from the byte table -> 32 state MFMAs in TWO 2-deep
//   chains (accA: chunks 0,1 seeded by the window term wacc computed last
//   step; accB: chunks 2,3 from zero) -> short epilogue -> L2 self-gather
//   (one bit/lane). The gather's ~250cy latency shadow is filled with next
//   step's 8 window MFMAs (into the wacc ping-pong) + popcll bias term —
//   this work is FREE here, which is why the R2 window-hoist to a prep
//   kernel was a net loss. Raw s_barrier drains lgkmcnt only; global
//   prefetches (wbits) stay in flight.
__global__ __launch_bounds__(256, 1) void scan_heads(
    const uint4* __restrict__ bfrag,
    const unsigned* __restrict__ packed32,
    const unsigned long long* __restrict__ wbits,
    const int* __restrict__ head_conn,
    const int* __restrict__ head_coeffs,
    const float* __restrict__ head_mem,
    float* __restrict__ out) {
  __shared__ __align__(16) unsigned char ab[2][256];   // state bits as i8 bytes
  __shared__ __align__(16) unsigned mcnt[2][4];        // per-chunk popcnt*32896
  const int tid = threadIdx.x;
  const int b = blockIdx.x;
  const int w = tid >> 6, l = tid & 63;
  const int qq = l >> 4;
  const int j = 64 * w + l;

  // one-time: 40 static B-fragments (tiles 4w..4w+3, kappa 0..4)
  v4i bf[4][5][2];
#pragma unroll
  for (int i = 0; i < 4; ++i)
#pragma unroll
    for (int k = 0; k < 5; ++k)
#pragma unroll
      for (int h = 0; h < 2; ++h) {
        int mf = ((4 * w + i) * 5 + k) * 2 + h;
        bf[i][k][h] = __builtin_bit_cast(v4i, bfrag[mf * 64 + l]);
      }

  ab[0][tid] = (unsigned char)0;            // state0 = 0
  if (tid < 4) mcnt[0][tid] = 0u;

  const unsigned* pkrow = packed32 + ((size_t)j << 11);
  unsigned long long wcur = wbits[b * 128];

  // prologue: t=0 window term into wacc[0], bias term for t=0
  v4i wacc[2][4][2];
  unsigned wcorr[2];
  {
    v4i aw = expand16((unsigned)((wcur >> (16 * qq)) & 0xFFFFu));
    v4i z = (v4i){0, 0, 0, 0};
#pragma unroll
    for (int i = 0; i < 4; ++i)
#pragma unroll
      for (int h = 0; h < 2; ++h)
        wacc[0][i][h] = __builtin_amdgcn_mfma_i32_16x16x64_i8(aw, bf[i][0][h], z, 0, 0, 0);
    wcorr[0] = (unsigned)__popcll(wcur) * 32896u;
  }
  __syncthreads();

#pragma unroll 2
  for (int t = 0; t < T_; ++t) {
    const int cur = t & 1, nxt = cur ^ 1;

    // prefetch next step's window row (independent, issued early)
    int tn = (t + 1 < T_) ? t + 1 : t;
    unsigned long long wnext = wbits[b * 128 + tn];

    // LDS reads first: 4 broadcast A-frags + popcount fixups
    const unsigned char* abase = &ab[cur][16 * qq];
    v4i a0 = *(const v4i*)(abase);
    v4i a1 = *(const v4i*)(abase + 64);
    v4i a2 = *(const v4i*)(abase + 128);
    v4i a3 = *(const v4i*)(abase + 192);
    uint4 cz = *((const uint4*)&mcnt[cur][0]);

    // 32 state MFMAs, two 2-deep chains per (tile,h).
    // accA seeded by the window contribution (computed last iteration).
    v4i z = (v4i){0, 0, 0, 0};
    v4i accA[4][2], accB[4][2];
#pragma unroll
    for (int i = 0; i < 4; ++i) {
      accA[i][0] = __builtin_amdgcn_mfma_i32_16x16x64_i8(a0, bf[i][1][0], wacc[cur][i][0], 0, 0, 0);
      accA[i][1] = __builtin_amdgcn_mfma_i32_16x16x64_i8(a0, bf[i][1][1], wacc[cur][i][1], 0, 0, 0);
      accB[i][0] = __builtin_amdgcn_mfma_i32_16x16x64_i8(a2, bf[i][3][0], z, 0, 0, 0);
      accB[i][1] = __builtin_amdgcn_mfma_i32_16x16x64_i8(a2, bf[i][3][1], z, 0, 0, 0);
    }
#pragma unroll
    for (int i = 0; i < 4; ++i) {
      accA[i][0] = __builtin_amdgcn_mfma_i32_16x16x64_i8(a1, bf[i][2][0], accA[i][0], 0, 0, 0);
      accA[i][1] = __builtin_amdgcn_mfma_i32_16x16x64_i8(a1, bf[i][2][1], accA[i][1], 0, 0, 0);
      accB[i][0] = __builtin_amdgcn_mfma_i32_16x16x64_i8(a3, bf[i][4][0], accB[i][0], 0, 0, 0);
      accB[i][1] = __builtin_amdgcn_mfma_i32_16x16x64_i8(a3, bf[i][4][1], accB[i][1], 0, 0, 0);
    }

    // epilogue: lane l owns state j = 64w+l -> tile i = l>>4, col l&15, reg 0
    unsigned csum = cz.x + cz.y + cz.z + cz.w + wcorr[cur];
    unsigned tv0 = ((unsigned)accA[0][0][0] + (unsigned)accB[0][0][0]) +
                   (((unsigned)accA[0][1][0] + (unsigned)accB[0][1][0]) << 8);
    unsigned tv1 = ((unsigned)accA[1][0][0] + (unsigned)accB[1][0][0]) +
                   (((unsigned)accA[1][1][0] + (unsigned)accB[1][1][0]) << 8);
    unsigned tv2 = ((unsigned)accA[2][0][0] + (unsigned)accB[2][0][0]) +
                   (((unsigned)accA[2][1][0] + (unsigned)accB[2][1][0]) << 8);
    unsigned tv3 = ((unsigned)accA[3][0][0] + (unsigned)accB[3][0][0]) +
                   (((unsigned)accA[3][1][0] + (unsigned)accB[3][1][0]) << 8);
    unsigned t01 = (l & 16) ? tv1 : tv0;
    unsigned t23 = (l & 16) ? tv3 : tv2;
    unsigned ad = (((l & 32) ? t23 : t01) + csum) & 0xFFFFu;

    // self-gather: one bit per lane, 256 per block (L2-resident table)
    unsigned word = pkrow[ad >> 5];

    // fill the gather latency shadow: next step's window MFMAs + bias term
    {
      v4i aw = expand16((unsigned)((wnext >> (16 * qq)) & 0xFFFFu));
#pragma unroll
      for (int i = 0; i < 4; ++i)
#pragma unroll
        for (int h = 0; h < 2; ++h)
          wacc[nxt][i][h] = __builtin_amdgcn_mfma_i32_16x16x64_i8(aw, bf[i][0][h], z, 0, 0, 0);
      wcorr[nxt] = (unsigned)__popcll(wnext) * 32896u;
    }

    unsigned bitv = (word >> (ad & 31)) & 1u;
    unsigned long long mq = __ballot(bitv != 0u);
    ab[nxt][j] = (unsigned char)bitv;
    if (l == 0) mcnt[nxt][w] = (unsigned)__popcll(mq) * 32896u;

    // raw barrier: drain LDS only; global prefetches stay in flight
    asm volatile("s_waitcnt lgkmcnt(0)" ::: "memory");
    __builtin_amdgcn_sched_barrier(0);
    __builtin_amdgcn_s_barrier();
    __builtin_amdgcn_sched_barrier(0);

    wcur = wnext;
  }

  // ---- heads (wave 0): only the selected head per batch row
  if (w == 0) {
    // wcur == window row t=127 (tn clamps at the last step)
    int h = (int)((((wcur >> 61) & 1) << 2) | (((wcur >> 62) & 1) << 1) |
                  ((wcur >> 63) & 1));
    int ho = h * 64 + l;
    const int4* cn4 = (const int4*)(head_conn + ho * 8);
    const int4* cf4 = (const int4*)(head_coeffs + ho * 8);
    int4 cna = cn4[0], cnb = cn4[1];
    int4 cfa = cf4[0], cfb = cf4[1];
    int cns[8] = {cna.x, cna.y, cna.z, cna.w, cnb.x, cnb.y, cnb.z, cnb.w};
    int cfs[8] = {cfa.x, cfa.y, cfa.z, cfa.w, cfb.x, cfb.y, cfb.z, cfb.w};
    unsigned addr = 0;
#pragma unroll
    for (int k = 0; k < 8; ++k) {
      addr += (unsigned)ab[T_ & 1][cns[k]] * (unsigned)cfs[k];
    }
    addr &= 0xFFFFu;
    out[b * 64 + l] = head_mem[((size_t)ho << 16) + addr];
  }
}

extern "C" void kernel_launch(void* const* d_in, const int* in_sizes, int n_in,
                              void* d_out, int out_size, void* d_ws, size_t ws_size,
                              hipStream_t stream) {
  const int*   bits         = (const int*)d_in[0];
  const int*   state_coeffs = (const int*)d_in[1];
  const float* state_mem    = (const float*)d_in[2];
  const int*   head_conn    = (const int*)d_in[3];
  const int*   head_coeffs  = (const int*)d_in[4];
  const float* head_mem     = (const float*)d_in[5];
  float* out = (float*)d_out;

  char* ws = (char*)d_ws;
  uint4*              bfrag  = (uint4*)ws;                              // 160 KiB
  unsigned long long* wbits  = (unsigned long long*)(ws + (160 << 10)); // 128 KiB
  unsigned*           packed = (unsigned*)(ws + (288 << 10));           // 2 MiB

  prep_bfrag<<<40, 256, 0, stream>>>(state_coeffs, bfrag);
  prep_wbits<<<4096, 256, 0, stream>>>(bits, wbits);
  prep_bitpack<<<2048, 256, 0, stream>>>(state_mem, (unsigned long long*)packed);
  scan_heads<<<128, 256, 0, stream>>>(bfrag, packed, wbits,
                                      head_conn, head_coeffs, head_mem, out);
}

// Round 5
// 319.364 us; speedup vs baseline: 1.0447x; 1.0014x over previous
//
#include <hip/hip_runtime.h>
#include <stdint.h>

#define T_ 128

typedef int v4i __attribute__((ext_vector_type(4)));

// ---------------------------------------------------------------------------
// prep 1: static B-fragments for mfma_i32_16x16x64_i8, biased i8 (byte-128).
// Fragment mf = (tau*5 + kappa)*2 + h. Lane l holds n = l&15,
// k-slots kin = (l>>4)*16 + 4r + b — identical slot->k map as scan's A, so
// any HW k-permutation cancels in the dot.
__global__ void prep_bfrag(const int* __restrict__ sc, uint4* __restrict__ bf) {
  int gid = blockIdx.x * 256 + threadIdx.x;
  if (gid >= 160 * 64) return;
  int mf = gid >> 6, l = gid & 63;
  int tau = mf / 10, rem = mf % 10;
  int kap = rem >> 1, h = rem & 1;
  int j = 16 * tau + (l & 15);
  int kinb = (l >> 4) * 16;
  unsigned wout[4];
#pragma unroll
  for (int r = 0; r < 4; ++r) {
    unsigned wrd = 0;
#pragma unroll
    for (int be = 0; be < 4; ++be) {
      int kin = kinb + 4 * r + be;
      int col = (kap == 0) ? kin : 64 + ((kap - 1) << 6) + kin;
      unsigned c = (unsigned)sc[j * 320 + col];
      unsigned byte = (h ? (c >> 8) : c) & 0xFFu;
      byte = (byte - 128u) & 0xFFu;
      wrd |= byte << (8 * be);
    }
    wout[r] = wrd;
  }
  bf[gid] = make_uint4(wout[0], wout[1], wout[2], wout[3]);
}

// prep 2: window bits packed to u64 per (b,t)
__global__ void prep_wbits(const int* __restrict__ bits,
                           unsigned long long* __restrict__ wb) {
  int gid = blockIdx.x * 256 + threadIdx.x;
  int wv = gid >> 6, lane = gid & 63;
  unsigned long long m = __ballot(bits[gid] != 0);
  if (lane == 0) wb[wv] = m;
}

// prep 3: bitpack (state_mem >= 0.5) -> 2 MiB table (L2-resident for scan)
__global__ void prep_bitpack(const float* __restrict__ sm,
                             unsigned long long* __restrict__ packed) {
  int base = blockIdx.x * (256 * 32) + threadIdx.x;
  int lane = threadIdx.x & 63;
#pragma unroll 1
  for (int it = 0; it < 32; ++it) {
    int idx = base + it * 256;
    float v = sm[idx];
    unsigned long long m = __ballot(v >= 0.5f);
    if (lane == 0) packed[idx >> 6] = m;
  }
}

// ---------------------------------------------------------------------------
// per-lane expand of a 16-bit slice into an i8 {0,1} A-fragment (window only)
static __device__ __forceinline__ v4i expand16(unsigned b16) {
  v4i a;
#pragma unroll
  for (int r = 0; r < 4; ++r) {
    unsigned nib = (b16 >> (4 * r)) & 0xFu;
    a[r] = (int)((nib * 0x00204081u) & 0x01010101u);
  }
  return a;
}

// ---------------------------------------------------------------------------
// scan + heads: 1 block per batch row, 4 waves of 64. Wave w owns states
// j in [64w, 64w+64). Per step:
//   ds_read A-frags from byte table -> 32 state MFMAs in FOUR independent
//   1-deep chains (accP seeded by the window term computed last step in the
//   gather shadow) -> short epilogue -> L2 self-gather (one bit/lane) ->
//   window MFMAs for t+1 in the gather latency shadow -> byte write ->
//   lgkmcnt-only barrier (global prefetches stay in flight).
// R5: all 40 B-fragments are PINNED in VGPRs via opaque asm — R4's
// VGPR_Count=124 proved the compiler was rematerializing bfrag[] loads
// inside the loop (FETCH 9.6MB vs ~3MB expected), injecting L2 latency
// into the per-step chain.
__global__ __launch_bounds__(256, 1) void scan_heads(
    const uint4* __restrict__ bfrag,
    const unsigned* __restrict__ packed32,
    const unsigned long long* __restrict__ wbits,
    const int* __restrict__ head_conn,
    const int* __restrict__ head_coeffs,
    const float* __restrict__ head_mem,
    float* __restrict__ out) {
  __shared__ __align__(16) unsigned char ab[2][256];   // state bits as i8 bytes
  __shared__ __align__(16) unsigned mcnt[2][4];        // per-chunk popcnt*32896
  const int tid = threadIdx.x;
  const int b = blockIdx.x;
  const int w = tid >> 6, l = tid & 63;
  const int qq = l >> 4;
  const int j = 64 * w + l;

  // one-time: 40 static B-fragments (tiles 4w..4w+3, kappa 0..4)
  v4i bf[4][5][2];
#pragma unroll
  for (int i = 0; i < 4; ++i)
#pragma unroll
    for (int k = 0; k < 5; ++k)
#pragma unroll
      for (int h = 0; h < 2; ++h) {
        int mf = ((4 * w + i) * 5 + k) * 2 + h;
        bf[i][k][h] = __builtin_bit_cast(v4i, bfrag[mf * 64 + l]);
      }
  // pin them: opaque to the optimizer -> cannot rematerialize the loads,
  // must keep all 160 VGPRs live (512 available at 1 wave/EU).
#pragma unroll
  for (int i = 0; i < 4; ++i)
#pragma unroll
    for (int k = 0; k < 5; ++k)
#pragma unroll
      for (int h = 0; h < 2; ++h)
        asm volatile("" : "+v"(bf[i][k][h]));

  ab[0][tid] = (unsigned char)0;            // state0 = 0
  if (tid < 4) mcnt[0][tid] = 0u;

  const unsigned* pkrow = packed32 + ((size_t)j << 11);
  unsigned long long wcur = wbits[b * 128];

  // prologue: t=0 window term + bias term
  v4i wacc[4][2];
  unsigned wcorr;
  {
    v4i aw = expand16((unsigned)((wcur >> (16 * qq)) & 0xFFFFu));
    v4i z = (v4i){0, 0, 0, 0};
#pragma unroll
    for (int i = 0; i < 4; ++i)
#pragma unroll
      for (int h = 0; h < 2; ++h)
        wacc[i][h] = __builtin_amdgcn_mfma_i32_16x16x64_i8(aw, bf[i][0][h], z, 0, 0, 0);
    wcorr = (unsigned)__popcll(wcur) * 32896u;
  }
  __syncthreads();

#pragma unroll 2
  for (int t = 0; t < T_; ++t) {
    const int cur = t & 1, nxt = cur ^ 1;

    // prefetch next step's window row (independent, issued early)
    int tn = (t + 1 < T_) ? t + 1 : t;
    unsigned long long wnext = wbits[b * 128 + tn];

    // LDS reads first: 4 broadcast A-frags + popcount fixups
    const unsigned char* abase = &ab[cur][16 * qq];
    v4i a0 = *(const v4i*)(abase);
    v4i a1 = *(const v4i*)(abase + 64);
    v4i a2 = *(const v4i*)(abase + 128);
    v4i a3 = *(const v4i*)(abase + 192);
    uint4 cz = *((const uint4*)&mcnt[cur][0]);

    // 32 state MFMAs, four independent 1-deep chains per (tile,h).
    // accP seeded by the window contribution (computed last iteration).
    v4i z = (v4i){0, 0, 0, 0};
    v4i accP[4][2], accQ[4][2], accR[4][2], accS[4][2];
#pragma unroll
    for (int i = 0; i < 4; ++i) {
      accP[i][0] = __builtin_amdgcn_mfma_i32_16x16x64_i8(a0, bf[i][1][0], wacc[i][0], 0, 0, 0);
      accP[i][1] = __builtin_amdgcn_mfma_i32_16x16x64_i8(a0, bf[i][1][1], wacc[i][1], 0, 0, 0);
      accQ[i][0] = __builtin_amdgcn_mfma_i32_16x16x64_i8(a1, bf[i][2][0], z, 0, 0, 0);
      accQ[i][1] = __builtin_amdgcn_mfma_i32_16x16x64_i8(a1, bf[i][2][1], z, 0, 0, 0);
      accR[i][0] = __builtin_amdgcn_mfma_i32_16x16x64_i8(a2, bf[i][3][0], z, 0, 0, 0);
      accR[i][1] = __builtin_amdgcn_mfma_i32_16x16x64_i8(a2, bf[i][3][1], z, 0, 0, 0);
      accS[i][0] = __builtin_amdgcn_mfma_i32_16x16x64_i8(a3, bf[i][4][0], z, 0, 0, 0);
      accS[i][1] = __builtin_amdgcn_mfma_i32_16x16x64_i8(a3, bf[i][4][1], z, 0, 0, 0);
    }

    // epilogue: lane l owns state j = 64w+l -> tile i = l>>4, col l&15, reg 0
    unsigned csum = cz.x + cz.y + cz.z + cz.w + wcorr;
    unsigned tv0 = ((unsigned)accP[0][0][0] + (unsigned)accQ[0][0][0] +
                    (unsigned)accR[0][0][0] + (unsigned)accS[0][0][0]) +
                   (((unsigned)accP[0][1][0] + (unsigned)accQ[0][1][0] +
                     (unsigned)accR[0][1][0] + (unsigned)accS[0][1][0]) << 8);
    unsigned tv1 = ((unsigned)accP[1][0][0] + (unsigned)accQ[1][0][0] +
                    (unsigned)accR[1][0][0] + (unsigned)accS[1][0][0]) +
                   (((unsigned)accP[1][1][0] + (unsigned)accQ[1][1][0] +
                     (unsigned)accR[1][1][0] + (unsigned)accS[1][1][0]) << 8);
    unsigned tv2 = ((unsigned)accP[2][0][0] + (unsigned)accQ[2][0][0] +
                    (unsigned)accR[2][0][0] + (unsigned)accS[2][0][0]) +
                   (((unsigned)accP[2][1][0] + (unsigned)accQ[2][1][0] +
                     (unsigned)accR[2][1][0] + (unsigned)accS[2][1][0]) << 8);
    unsigned tv3 = ((unsigned)accP[3][0][0] + (unsigned)accQ[3][0][0] +
                    (unsigned)accR[3][0][0] + (unsigned)accS[3][0][0]) +
                   (((unsigned)accP[3][1][0] + (unsigned)accQ[3][1][0] +
                     (unsigned)accR[3][1][0] + (unsigned)accS[3][1][0]) << 8);
    unsigned t01 = (l & 16) ? tv1 : tv0;
    unsigned t23 = (l & 16) ? tv3 : tv2;
    unsigned ad = (((l & 32) ? t23 : t01) + csum) & 0xFFFFu;

    // self-gather: one bit per lane, 256 per block (L2-resident table)
    unsigned word = pkrow[ad >> 5];

    // fill the gather latency shadow: next step's window MFMAs + bias term
    {
      v4i aw = expand16((unsigned)((wnext >> (16 * qq)) & 0xFFFFu));
#pragma unroll
      for (int i = 0; i < 4; ++i)
#pragma unroll
        for (int h = 0; h < 2; ++h)
          wacc[i][h] = __builtin_amdgcn_mfma_i32_16x16x64_i8(aw, bf[i][0][h], z, 0, 0, 0);
      wcorr = (unsigned)__popcll(wnext) * 32896u;
    }

    unsigned bitv = (word >> (ad & 31)) & 1u;
    unsigned long long mq = __ballot(bitv != 0u);
    ab[nxt][j] = (unsigned char)bitv;
    if (l == 0) mcnt[nxt][w] = (unsigned)__popcll(mq) * 32896u;

    // raw barrier: drain LDS only; global prefetches stay in flight
    asm volatile("s_waitcnt lgkmcnt(0)" ::: "memory");
    __builtin_amdgcn_sched_barrier(0);
    __builtin_amdgcn_s_barrier();
    __builtin_amdgcn_sched_barrier(0);

    wcur = wnext;
  }

  // ---- heads (wave 0): only the selected head per batch row
  if (w == 0) {
    // wcur == window row t=127 (tn clamps at the last step)
    int h = (int)((((wcur >> 61) & 1) << 2) | (((wcur >> 62) & 1) << 1) |
                  ((wcur >> 63) & 1));
    int ho = h * 64 + l;
    const int4* cn4 = (const int4*)(head_conn + ho * 8);
    const int4* cf4 = (const int4*)(head_coeffs + ho * 8);
    int4 cna = cn4[0], cnb = cn4[1];
    int4 cfa = cf4[0], cfb = cf4[1];
    int cns[8] = {cna.x, cna.y, cna.z, cna.w, cnb.x, cnb.y, cnb.z, cnb.w};
    int cfs[8] = {cfa.x, cfa.y, cfa.z, cfa.w, cfb.x, cfb.y, cfb.z, cfb.w};
    unsigned addr = 0;
#pragma unroll
    for (int k = 0; k < 8; ++k) {
      addr += (unsigned)ab[T_ & 1][cns[k]] * (unsigned)cfs[k];
    }
    addr &= 0xFFFFu;
    out[b * 64 + l] = head_mem[((size_t)ho << 16) + addr];
  }
}

extern "C" void kernel_launch(void* const* d_in, const int* in_sizes, int n_in,
                              void* d_out, int out_size, void* d_ws, size_t ws_size,
                              hipStream_t stream) {
  const int*   bits         = (const int*)d_in[0];
  const int*   state_coeffs = (const int*)d_in[1];
  const float* state_mem    = (const float*)d_in[2];
  const int*   head_conn    = (const int*)d_in[3];
  const int*   head_coeffs  = (const int*)d_in[4];
  const float* head_mem     = (const float*)d_in[5];
  float* out = (float*)d_out;

  char* ws = (char*)d_ws;
  uint4*              bfrag  = (uint4*)ws;                              // 160 KiB
  unsigned long long* wbits  = (unsigned long long*)(ws + (160 << 10)); // 128 KiB
  unsigned*           packed = (unsigned*)(ws + (288 << 10));           // 2 MiB

  prep_bfrag<<<40, 256, 0, stream>>>(state_coeffs, bfrag);
  prep_wbits<<<4096, 256, 0, stream>>>(bits, wbits);
  prep_bitpack<<<2048, 256, 0, stream>>>(state_mem, (unsigned long long*)packed);
  scan_heads<<<128, 256, 0, stream>>>(bfrag, packed, wbits,
                                      head_conn, head_coeffs, head_mem, out);
}